// Round 4
// baseline (1016.684 us; speedup 1.0000x reference)
//
#include <hip/hip_runtime.h>

typedef unsigned short u16;
typedef float f32x4 __attribute__((ext_vector_type(4)));
typedef short short8 __attribute__((ext_vector_type(8)));

#define XRES 512
#define TRES 64

// ws layout in u16 elements
#define WS_XY 0
#define WS_YT 8388608
#define WS_XT 9437184
#define WS_WF 10485760
#define WF1 0
#define WF2 8192
#define WF3 73728
#define WS_NEEDED_BYTES 21250048ull

__device__ __forceinline__ u16 f2bf(float f) {
  union { float f; unsigned u; } v; v.f = f;
  unsigned r = v.u + 0x7FFFu + ((v.u >> 16) & 1u);
  return (u16)(r >> 16);
}
__device__ __forceinline__ float bf2f(u16 u) {
  union { unsigned u; float f; } v; v.u = ((unsigned)u) << 16;
  return v.f;
}

// MFMA via inline asm (signature-proof); dataflow operands keep scheduling correct.
__device__ __forceinline__ f32x4 mfma16x16x32_bf16(short8 a, short8 b, f32x4 c) {
  f32x4 d;
  asm("v_mfma_f32_16x16x32_bf16 %0, %1, %2, %3" : "=v"(d) : "v"(a), "v"(b), "v"(c));
  return d;
}

// ======================= FALLBACK KERNEL (pure VALU, used only if ws too small) ===============
__device__ __forceinline__ void sample_direct(const float* __restrict__ pl, int H, int W,
                                              float gx, float gy, float* acc) {
  float ix = (gx + 1.0f) * 0.5f * (float)(W - 1);
  float iy = (gy + 1.0f) * 0.5f * (float)(H - 1);
  float x0f = floorf(ix), y0f = floorf(iy);
  float wx = ix - x0f, wy = iy - y0f;
  int x0 = (int)x0f, y0 = (int)y0f;
  x0 = max(0, min(x0, W - 1)); y0 = max(0, min(y0, H - 1));
  int x1 = min(x0 + 1, W - 1), y1 = min(y0 + 1, H - 1);
  float w00 = (1.0f - wx) * (1.0f - wy), w01 = wx * (1.0f - wy);
  float w10 = (1.0f - wx) * wy,          w11 = wx * wy;
  const int HW = H * W;
  const int i00 = y0 * W + x0, i01 = y0 * W + x1, i10 = y1 * W + x0, i11 = y1 * W + x1;
#pragma unroll
  for (int c = 0; c < 32; ++c) {
    const float* pc = pl + c * HW;
    acc[c] += w00 * pc[i00] + w01 * pc[i01] + w10 * pc[i10] + w11 * pc[i11];
  }
}

__device__ void layer_valu(const float* hin, float* hout, const float* __restrict__ w,
                           const float* __restrict__ b) {
  for (int pass = 0; pass < 8; ++pass) {
    float acc[32];
#pragma unroll
    for (int jx = 0; jx < 32; ++jx) acc[jx] = b[pass * 32 + jx];
    for (int k = 0; k < 256; ++k) {
      const float hk = hin[k];
      const float* wr = w + k * 256 + pass * 32;
#pragma unroll
      for (int jx = 0; jx < 32; ++jx) acc[jx] = fmaf(hk, wr[jx], acc[jx]);
    }
#pragma unroll
    for (int jx = 0; jx < 32; ++jx) {
      float v = acc[jx];
      hout[pass * 32 + jx] = v > 0.f ? v : 0.01f * v;
    }
  }
}

__global__ void triplane_safe(const float* __restrict__ coords,
                              const float* __restrict__ xy, const float* __restrict__ yt,
                              const float* __restrict__ xt,
                              const float* __restrict__ w1, const float* __restrict__ b1,
                              const float* __restrict__ w2, const float* __restrict__ b2,
                              const float* __restrict__ w3, const float* __restrict__ b3,
                              const float* __restrict__ w4, const float* __restrict__ b4,
                              float* __restrict__ out) {
  const int pg = blockIdx.x * 256 + threadIdx.x;
  const float x  = coords[pg * 3 + 0];
  const float y  = coords[pg * 3 + 1];
  const float tt = coords[pg * 3 + 2];
  float feats[32];
#pragma unroll
  for (int c = 0; c < 32; ++c) feats[c] = 0.f;
  sample_direct(xy, XRES, XRES, x, y,  feats);
  sample_direct(yt, TRES, XRES, y, tt, feats);
  sample_direct(xt, TRES, XRES, x, tt, feats);

  float hA[256], hB[256];
  for (int pass = 0; pass < 8; ++pass) {
    float acc[32];
#pragma unroll
    for (int jx = 0; jx < 32; ++jx) acc[jx] = b1[pass * 32 + jx];
#pragma unroll
    for (int k = 0; k < 32; ++k) {
      const float fk = feats[k];
      const float* wr = w1 + k * 256 + pass * 32;
#pragma unroll
      for (int jx = 0; jx < 32; ++jx) acc[jx] = fmaf(fk, wr[jx], acc[jx]);
    }
#pragma unroll
    for (int jx = 0; jx < 32; ++jx) {
      float v = acc[jx];
      hA[pass * 32 + jx] = v > 0.f ? v : 0.01f * v;
    }
  }
  layer_valu(hA, hB, w2, b2);
  layer_valu(hB, hA, w3, b3);
  float a0 = b4[0], a1 = b4[1];
  for (int k = 0; k < 256; ++k) {
    a0 = fmaf(hA[k], w4[k * 2 + 0], a0);
    a1 = fmaf(hA[k], w4[k * 2 + 1], a1);
  }
  out[pg * 2 + 0] = 1.f / (1.f + __expf(-a0));
  out[pg * 2 + 1] = 1.f / (1.f + __expf(-a1));
}

// ======================= FAST PATH =======================
__global__ void prep_planes(const float* __restrict__ xy, const float* __restrict__ yt,
                            const float* __restrict__ xt, u16* __restrict__ ws) {
  int i = blockIdx.x * 256 + threadIdx.x;  // 0..327679
  const float* src; u16* dst; int HW; int idx;
  if (i < 262144)      { src = xy; dst = ws + WS_XY; HW = 262144; idx = i; }
  else if (i < 294912) { src = yt; dst = ws + WS_YT; HW = 32768;  idx = i - 262144; }
  else                 { src = xt; dst = ws + WS_XT; HW = 32768;  idx = i - 294912; }
  u16 tmp[32];
#pragma unroll
  for (int c = 0; c < 32; ++c) tmp[c] = f2bf(src[c * HW + idx]);
  short8* o = (short8*)(dst + (long)idx * 32);
#pragma unroll
  for (int s = 0; s < 4; ++s) o[s] = *(short8*)(tmp + s * 8);
}

// weights [K,256] f32 -> B-fragment chunks: chunk L=(CT*KSTEPS+ks)*64+lane holds 8 bf16
// w[k][col], col=CT*16+(lane&15), k=ks*32+(lane>>4)*8+j  (same slot->k map as A side)
__global__ void prep_weights(const float* __restrict__ w1, const float* __restrict__ w2,
                             const float* __restrict__ w3, u16* __restrict__ wf) {
  int tid = blockIdx.x * 256 + threadIdx.x;  // 0..17407
  const float* src; int KS; int local; int dstbase;
  if (tid < 1024)      { src = w1; KS = 1; local = tid;        dstbase = WF1; }
  else if (tid < 9216) { src = w2; KS = 8; local = tid - 1024; dstbase = WF2; }
  else                 { src = w3; KS = 8; local = tid - 9216; dstbase = WF3; }
  int lane = local & 63, blk = local >> 6;
  int ks = blk % KS, CT = blk / KS;
  int col = CT * 16 + (lane & 15);
  int kb = ks * 32 + (lane >> 4) * 8;
  u16 tmp[8];
#pragma unroll
  for (int j = 0; j < 8; ++j) tmp[j] = f2bf(src[(kb + j) * 256 + col]);
  *(short8*)(wf + dstbase + local * 8) = *(short8*)tmp;
}

__device__ __forceinline__ void sample_plane(const u16* __restrict__ pl, int H, int W,
                                             float gx, float gy, int c0, float* acc) {
  float ix = (gx + 1.0f) * 0.5f * (float)(W - 1);
  float iy = (gy + 1.0f) * 0.5f * (float)(H - 1);
  float x0f = floorf(ix), y0f = floorf(iy);
  float wx = ix - x0f, wy = iy - y0f;
  int x0 = (int)x0f, y0 = (int)y0f;
  x0 = max(0, min(x0, W - 1)); y0 = max(0, min(y0, H - 1));
  int x1 = min(x0 + 1, W - 1);
  int y1 = min(y0 + 1, H - 1);
  short8 v00 = *(const short8*)(pl + (y0 * W + x0) * 32 + c0);
  short8 v01 = *(const short8*)(pl + (y0 * W + x1) * 32 + c0);
  short8 v10 = *(const short8*)(pl + (y1 * W + x0) * 32 + c0);
  short8 v11 = *(const short8*)(pl + (y1 * W + x1) * 32 + c0);
  float w00 = (1.0f - wx) * (1.0f - wy), w01 = wx * (1.0f - wy);
  float w10 = (1.0f - wx) * wy,          w11 = wx * wy;
#pragma unroll
  for (int j = 0; j < 8; ++j)
    acc[j] += w00 * bf2f((u16)v00[j]) + w01 * bf2f((u16)v01[j])
            + w10 * bf2f((u16)v10[j]) + w11 * bf2f((u16)v11[j]);
}

// [32 x 32*KSTEPS] @ [32*KSTEPS x 256], bias+leaky, bf16 out to LDS.
// LDS act layout: [32][256] bf16 rows (512 B), byte ^= ((row&7)<<4) XOR swizzle (T2).
template <int KSTEPS>
__device__ __forceinline__ void layer_gemm(const u16* src, u16* dst,
                                           const u16* __restrict__ wf,
                                           const float* __restrict__ bias,
                                           int wave, int lane) {
  const int r16 = lane & 15, kq = lane >> 4;
  f32x4 acc[2][4];
#pragma unroll
  for (int rt = 0; rt < 2; ++rt)
#pragma unroll
    for (int ct = 0; ct < 4; ++ct) acc[rt][ct] = (f32x4){0.f, 0.f, 0.f, 0.f};

#pragma unroll
  for (int ks = 0; ks < KSTEPS; ++ks) {
    const int kbyte = ks * 64 + kq * 16;
    short8 a[2], b[4];
#pragma unroll
    for (int rt = 0; rt < 2; ++rt) {
      const int row = rt * 16 + r16;
      a[rt] = *(const short8*)((const char*)src + row * 512 + (kbyte ^ ((row & 7) << 4)));
    }
#pragma unroll
    for (int ct = 0; ct < 4; ++ct)
      b[ct] = *(const short8*)(wf + (((wave * 4 + ct) * KSTEPS + ks) * 64 + lane) * 8);
#pragma unroll
    for (int rt = 0; rt < 2; ++rt)
#pragma unroll
      for (int ct = 0; ct < 4; ++ct)
        acc[rt][ct] = mfma16x16x32_bf16(a[rt], b[ct], acc[rt][ct]);
  }
  // C/D layout: col = lane&15, row = (lane>>4)*4 + reg  [m89-verified]
#pragma unroll
  for (int ct = 0; ct < 4; ++ct) {
    const int col = wave * 64 + ct * 16 + r16;
    const float bv = bias[col];
#pragma unroll
    for (int rt = 0; rt < 2; ++rt)
#pragma unroll
      for (int q = 0; q < 4; ++q) {
        const int row = rt * 16 + kq * 4 + q;
        float v = acc[rt][ct][q] + bv;
        v = v > 0.f ? v : 0.01f * v;
        *(u16*)((char*)dst + row * 512 + ((col * 2) ^ ((row & 7) << 4))) = f2bf(v);
      }
  }
}

// fused main kernel: 32 points / block, 256 threads, 32 KiB LDS
__global__ void triplane_fused(const float* __restrict__ coords, const u16* __restrict__ ws,
                               const float* __restrict__ b1, const float* __restrict__ b2,
                               const float* __restrict__ b3, const float* __restrict__ w4,
                               const float* __restrict__ b4, float* __restrict__ out) {
  __shared__ u16 sA[32 * 256];
  __shared__ u16 sB[32 * 256];
  const int t = threadIdx.x;
  const int lane = t & 63, wave = t >> 6;
  const int pg0 = blockIdx.x * 32;

  if (t < 128) {
    const int p = t >> 2, cg = t & 3, c0 = cg * 8;
    const int pg = pg0 + p;
    const float x  = coords[pg * 3 + 0];
    const float y  = coords[pg * 3 + 1];
    const float tt = coords[pg * 3 + 2];
    float acc8[8];
#pragma unroll
    for (int j = 0; j < 8; ++j) acc8[j] = 0.f;
    sample_plane(ws + WS_XY, XRES, XRES, x, y,  c0, acc8);
    sample_plane(ws + WS_YT, TRES, XRES, y, tt, c0, acc8);
    sample_plane(ws + WS_XT, TRES, XRES, x, tt, c0, acc8);
    u16 packed[8];
#pragma unroll
    for (int j = 0; j < 8; ++j) packed[j] = f2bf(acc8[j]);
    *(short8*)((char*)sA + p * 512 + ((c0 * 2) ^ ((p & 7) << 4))) = *(short8*)packed;
  }
  __syncthreads();

  const u16* wfb = ws + WS_WF;
  layer_gemm<1>(sA, sB, wfb + WF1, b1, wave, lane);
  __syncthreads();
  layer_gemm<8>(sB, sA, wfb + WF2, b2, wave, lane);
  __syncthreads();
  layer_gemm<8>(sA, sB, wfb + WF3, b3, wave, lane);
  __syncthreads();

  if (t < 128) {
    const int p = t >> 2, cg = t & 3;
    const int pg = pg0 + p;
    float a0 = 0.f, a1 = 0.f;
#pragma unroll
    for (int kk = 0; kk < 8; ++kk) {
      const int k0 = cg * 64 + kk * 8;
      short8 h = *(const short8*)((const char*)sB + p * 512 + ((k0 * 2) ^ ((p & 7) << 4)));
#pragma unroll
      for (int j = 0; j < 8; ++j) {
        const float hv = bf2f((u16)h[j]);
        a0 = fmaf(hv, w4[(k0 + j) * 2 + 0], a0);
        a1 = fmaf(hv, w4[(k0 + j) * 2 + 1], a1);
      }
    }
    a0 += __shfl_xor(a0, 1, 4); a0 += __shfl_xor(a0, 2, 4);
    a1 += __shfl_xor(a1, 1, 4); a1 += __shfl_xor(a1, 2, 4);
    if (cg == 0) {
      out[pg * 2 + 0] = 1.f / (1.f + __expf(-(a0 + b4[0])));
      out[pg * 2 + 1] = 1.f / (1.f + __expf(-(a1 + b4[1])));
    }
  }
}

extern "C" void kernel_launch(void* const* d_in, const int* in_sizes, int n_in,
                              void* d_out, int out_size, void* d_ws, size_t ws_size,
                              hipStream_t stream) {
  (void)in_sizes; (void)n_in; (void)out_size;
  const float* coords = (const float*)d_in[0];
  const float* xy = (const float*)d_in[1];
  const float* yt = (const float*)d_in[2];
  const float* xt = (const float*)d_in[3];
  const float* w1 = (const float*)d_in[4];
  const float* b1 = (const float*)d_in[5];
  const float* w2 = (const float*)d_in[6];
  const float* b2 = (const float*)d_in[7];
  const float* w3 = (const float*)d_in[8];
  const float* b3 = (const float*)d_in[9];
  const float* w4 = (const float*)d_in[10];
  const float* b4 = (const float*)d_in[11];

  if (ws_size >= WS_NEEDED_BYTES && d_ws != nullptr) {
    u16* ws = (u16*)d_ws;
    prep_planes<<<1280, 256, 0, stream>>>(xy, yt, xt, ws);
    prep_weights<<<68, 256, 0, stream>>>(w1, w2, w3, ws + WS_WF);
    triplane_fused<<<32768, 256, 0, stream>>>(coords, ws, b1, b2, b3, w4, b4, (float*)d_out);
  } else {
    triplane_safe<<<4096, 256, 0, stream>>>(coords, xy, yt, xt, w1, b1, w2, b2, w3, b3, w4, b4,
                                            (float*)d_out);
  }
}

// Round 5
// 678.977 us; speedup vs baseline: 1.4974x; 1.4974x over previous
//
#include <hip/hip_runtime.h>

typedef unsigned short u16;
typedef float f32x4 __attribute__((ext_vector_type(4)));
typedef short short8 __attribute__((ext_vector_type(8)));
typedef short short4v __attribute__((ext_vector_type(4)));

#define XRES 512
#define TRES 64

// ws layout in u16 elements
#define WS_XY 0
#define WS_YT 8388608
#define WS_XT 9437184
#define WS_WF 10485760
#define WF1 0
#define WF2 8192
#define WF3 73728
#define WS_NEEDED_BYTES 21250048ull

__device__ __forceinline__ u16 f2bf(float f) {
  union { float f; unsigned u; } v; v.f = f;
  unsigned r = v.u + 0x7FFFu + ((v.u >> 16) & 1u);
  return (u16)(r >> 16);
}
__device__ __forceinline__ float bf2f(u16 u) {
  union { unsigned u; float f; } v; v.u = ((unsigned)u) << 16;
  return v.f;
}

// MFMA via inline asm (signature-proof); dataflow operands keep scheduling correct.
__device__ __forceinline__ f32x4 mfma16x16x32_bf16(short8 a, short8 b, f32x4 c) {
  f32x4 d;
  asm("v_mfma_f32_16x16x32_bf16 %0, %1, %2, %3" : "=v"(d) : "v"(a), "v"(b), "v"(c));
  return d;
}

// ======================= FALLBACK KERNEL (pure VALU, used only if ws too small) ===============
__device__ __forceinline__ void sample_direct(const float* __restrict__ pl, int H, int W,
                                              float gx, float gy, float* acc) {
  float ix = (gx + 1.0f) * 0.5f * (float)(W - 1);
  float iy = (gy + 1.0f) * 0.5f * (float)(H - 1);
  float x0f = floorf(ix), y0f = floorf(iy);
  float wx = ix - x0f, wy = iy - y0f;
  int x0 = (int)x0f, y0 = (int)y0f;
  x0 = max(0, min(x0, W - 1)); y0 = max(0, min(y0, H - 1));
  int x1 = min(x0 + 1, W - 1), y1 = min(y0 + 1, H - 1);
  float w00 = (1.0f - wx) * (1.0f - wy), w01 = wx * (1.0f - wy);
  float w10 = (1.0f - wx) * wy,          w11 = wx * wy;
  const int HW = H * W;
  const int i00 = y0 * W + x0, i01 = y0 * W + x1, i10 = y1 * W + x0, i11 = y1 * W + x1;
#pragma unroll
  for (int c = 0; c < 32; ++c) {
    const float* pc = pl + c * HW;
    acc[c] += w00 * pc[i00] + w01 * pc[i01] + w10 * pc[i10] + w11 * pc[i11];
  }
}

__device__ void layer_valu(const float* hin, float* hout, const float* __restrict__ w,
                           const float* __restrict__ b) {
  for (int pass = 0; pass < 8; ++pass) {
    float acc[32];
#pragma unroll
    for (int jx = 0; jx < 32; ++jx) acc[jx] = b[pass * 32 + jx];
    for (int k = 0; k < 256; ++k) {
      const float hk = hin[k];
      const float* wr = w + k * 256 + pass * 32;
#pragma unroll
      for (int jx = 0; jx < 32; ++jx) acc[jx] = fmaf(hk, wr[jx], acc[jx]);
    }
#pragma unroll
    for (int jx = 0; jx < 32; ++jx) {
      float v = acc[jx];
      hout[pass * 32 + jx] = v > 0.f ? v : 0.01f * v;
    }
  }
}

__global__ void triplane_safe(const float* __restrict__ coords,
                              const float* __restrict__ xy, const float* __restrict__ yt,
                              const float* __restrict__ xt,
                              const float* __restrict__ w1, const float* __restrict__ b1,
                              const float* __restrict__ w2, const float* __restrict__ b2,
                              const float* __restrict__ w3, const float* __restrict__ b3,
                              const float* __restrict__ w4, const float* __restrict__ b4,
                              float* __restrict__ out) {
  const int pg = blockIdx.x * 256 + threadIdx.x;
  const float x  = coords[pg * 3 + 0];
  const float y  = coords[pg * 3 + 1];
  const float tt = coords[pg * 3 + 2];
  float feats[32];
#pragma unroll
  for (int c = 0; c < 32; ++c) feats[c] = 0.f;
  sample_direct(xy, XRES, XRES, x, y,  feats);
  sample_direct(yt, TRES, XRES, y, tt, feats);
  sample_direct(xt, TRES, XRES, x, tt, feats);

  float hA[256], hB[256];
  for (int pass = 0; pass < 8; ++pass) {
    float acc[32];
#pragma unroll
    for (int jx = 0; jx < 32; ++jx) acc[jx] = b1[pass * 32 + jx];
#pragma unroll
    for (int k = 0; k < 32; ++k) {
      const float fk = feats[k];
      const float* wr = w1 + k * 256 + pass * 32;
#pragma unroll
      for (int jx = 0; jx < 32; ++jx) acc[jx] = fmaf(fk, wr[jx], acc[jx]);
    }
#pragma unroll
    for (int jx = 0; jx < 32; ++jx) {
      float v = acc[jx];
      hA[pass * 32 + jx] = v > 0.f ? v : 0.01f * v;
    }
  }
  layer_valu(hA, hB, w2, b2);
  layer_valu(hB, hA, w3, b3);
  float a0 = b4[0], a1 = b4[1];
  for (int k = 0; k < 256; ++k) {
    a0 = fmaf(hA[k], w4[k * 2 + 0], a0);
    a1 = fmaf(hA[k], w4[k * 2 + 1], a1);
  }
  out[pg * 2 + 0] = 1.f / (1.f + __expf(-a0));
  out[pg * 2 + 1] = 1.f / (1.f + __expf(-a1));
}

// ======================= FAST PATH =======================
__global__ void prep_planes(const float* __restrict__ xy, const float* __restrict__ yt,
                            const float* __restrict__ xt, u16* __restrict__ ws) {
  int i = blockIdx.x * 256 + threadIdx.x;  // 0..327679
  const float* src; u16* dst; int HW; int idx;
  if (i < 262144)      { src = xy; dst = ws + WS_XY; HW = 262144; idx = i; }
  else if (i < 294912) { src = yt; dst = ws + WS_YT; HW = 32768;  idx = i - 262144; }
  else                 { src = xt; dst = ws + WS_XT; HW = 32768;  idx = i - 294912; }
  u16 tmp[32];
#pragma unroll
  for (int c = 0; c < 32; ++c) tmp[c] = f2bf(src[c * HW + idx]);
  short8* o = (short8*)(dst + (long)idx * 32);
#pragma unroll
  for (int s = 0; s < 4; ++s) o[s] = *(short8*)(tmp + s * 8);
}

// weights [K,256] f32 -> B-fragment chunks: chunk L=(CT*KSTEPS+ks)*64+lane holds 8 bf16
// w[k][col], col=CT*16+(lane&15), k=ks*32+(lane>>4)*8+j  (same slot->k map as A side)
__global__ void prep_weights(const float* __restrict__ w1, const float* __restrict__ w2,
                             const float* __restrict__ w3, u16* __restrict__ wf) {
  int tid = blockIdx.x * 256 + threadIdx.x;  // 0..17407
  const float* src; int KS; int local; int dstbase;
  if (tid < 1024)      { src = w1; KS = 1; local = tid;        dstbase = WF1; }
  else if (tid < 9216) { src = w2; KS = 8; local = tid - 1024; dstbase = WF2; }
  else                 { src = w3; KS = 8; local = tid - 9216; dstbase = WF3; }
  int lane = local & 63, blk = local >> 6;
  int ks = blk % KS, CT = blk / KS;
  int col = CT * 16 + (lane & 15);
  int kb = ks * 32 + (lane >> 4) * 8;
  u16 tmp[8];
#pragma unroll
  for (int j = 0; j < 8; ++j) tmp[j] = f2bf(src[(kb + j) * 256 + col]);
  *(short8*)(wf + dstbase + local * 8) = *(short8*)tmp;
}

// 4-channel bilinear sample from [H,W,C=32] bf16 plane
__device__ __forceinline__ void sample_plane4(const u16* __restrict__ pl, int H, int W,
                                              float gx, float gy, int c0, float* acc) {
  float ix = (gx + 1.0f) * 0.5f * (float)(W - 1);
  float iy = (gy + 1.0f) * 0.5f * (float)(H - 1);
  float x0f = floorf(ix), y0f = floorf(iy);
  float wx = ix - x0f, wy = iy - y0f;
  int x0 = (int)x0f, y0 = (int)y0f;
  x0 = max(0, min(x0, W - 1)); y0 = max(0, min(y0, H - 1));
  int x1 = min(x0 + 1, W - 1);
  int y1 = min(y0 + 1, H - 1);
  short4v v00 = *(const short4v*)(pl + (y0 * W + x0) * 32 + c0);
  short4v v01 = *(const short4v*)(pl + (y0 * W + x1) * 32 + c0);
  short4v v10 = *(const short4v*)(pl + (y1 * W + x0) * 32 + c0);
  short4v v11 = *(const short4v*)(pl + (y1 * W + x1) * 32 + c0);
  float w00 = (1.0f - wx) * (1.0f - wy), w01 = wx * (1.0f - wy);
  float w10 = (1.0f - wx) * wy,          w11 = wx * wy;
#pragma unroll
  for (int j = 0; j < 4; ++j)
    acc[j] += w00 * bf2f((u16)v00[j]) + w01 * bf2f((u16)v01[j])
            + w10 * bf2f((u16)v10[j]) + w11 * bf2f((u16)v11[j]);
}

// [32 x 32*KSTEPS] @ [32*KSTEPS x 256], bias+leaky, bf16 out to LDS.
// LDS act layout: [32][256] bf16 rows (512 B), byte ^= ((row&7)<<4) XOR swizzle (T2).
// A (LDS) and B (global/L2) fragments are double-buffered one ks-step ahead (T14).
template <int KSTEPS>
__device__ __forceinline__ void layer_gemm(const u16* src, u16* dst,
                                           const u16* __restrict__ wf,
                                           const float* __restrict__ bias,
                                           int wave, int lane) {
  const int r16 = lane & 15, kq = lane >> 4;
  f32x4 acc[2][4];
#pragma unroll
  for (int rt = 0; rt < 2; ++rt)
#pragma unroll
    for (int ct = 0; ct < 4; ++ct) acc[rt][ct] = (f32x4){0.f, 0.f, 0.f, 0.f};

  short8 aA[2], aB[2], bA[4], bB[4];

#define LDA(ks, dst_)                                                                   \
  {                                                                                     \
    const int kbyte_ = (ks) * 64 + kq * 16;                                             \
    _Pragma("unroll") for (int rt = 0; rt < 2; ++rt) {                                  \
      const int row_ = rt * 16 + r16;                                                   \
      dst_[rt] = *(const short8*)((const char*)src + row_ * 512 +                       \
                                  (kbyte_ ^ ((row_ & 7) << 4)));                        \
    }                                                                                   \
  }
#define LDB(ks, dst_)                                                                   \
  {                                                                                     \
    _Pragma("unroll") for (int ct = 0; ct < 4; ++ct)                                    \
        dst_[ct] = *(const short8*)(wf + (((wave * 4 + ct) * KSTEPS + (ks)) * 64 +      \
                                          lane) * 8);                                   \
  }

  LDA(0, aA); LDB(0, bA);
#pragma unroll
  for (int ks = 0; ks < KSTEPS; ++ks) {
    const bool even = (ks & 1) == 0;
    short8* ac = even ? aA : aB;
    short8* bc = even ? bA : bB;
    short8* an = even ? aB : aA;
    short8* bn = even ? bB : bA;
    if (ks + 1 < KSTEPS) { LDA(ks + 1, an); LDB(ks + 1, bn); }
#pragma unroll
    for (int rt = 0; rt < 2; ++rt)
#pragma unroll
      for (int ct = 0; ct < 4; ++ct)
        acc[rt][ct] = mfma16x16x32_bf16(ac[rt], bc[ct], acc[rt][ct]);
  }
#undef LDA
#undef LDB

  // C/D layout: col = lane&15, row = (lane>>4)*4 + reg  [m89-verified]
#pragma unroll
  for (int ct = 0; ct < 4; ++ct) {
    const int col = wave * 64 + ct * 16 + r16;
    const float bv = bias[col];
#pragma unroll
    for (int rt = 0; rt < 2; ++rt)
#pragma unroll
      for (int q = 0; q < 4; ++q) {
        const int row = rt * 16 + kq * 4 + q;
        float v = acc[rt][ct][q] + bv;
        v = v > 0.f ? v : 0.01f * v;
        *(u16*)((char*)dst + row * 512 + ((col * 2) ^ ((row & 7) << 4))) = f2bf(v);
      }
  }
}

// fused main kernel: 32 points / block, 256 threads, 32 KiB LDS
__global__ __launch_bounds__(256, 4) void triplane_fused(
    const float* __restrict__ coords, const u16* __restrict__ ws,
    const float* __restrict__ b1, const float* __restrict__ b2,
    const float* __restrict__ b3, const float* __restrict__ w4,
    const float* __restrict__ b4, float* __restrict__ out) {
  __shared__ u16 sA[32 * 256];
  __shared__ u16 sB[32 * 256];
  const int t = threadIdx.x;
  const int lane = t & 63, wave = t >> 6;
  const int pg0 = blockIdx.x * 32;

  // sampling: all 256 threads — 8 channel-groups of 4 per point
  {
    const int p = t >> 3, cg = t & 7, c0 = cg * 4;
    const int pg = pg0 + p;
    const float x  = coords[pg * 3 + 0];
    const float y  = coords[pg * 3 + 1];
    const float tt = coords[pg * 3 + 2];
    float acc4[4] = {0.f, 0.f, 0.f, 0.f};
    sample_plane4(ws + WS_XY, XRES, XRES, x, y,  c0, acc4);
    sample_plane4(ws + WS_YT, TRES, XRES, y, tt, c0, acc4);
    sample_plane4(ws + WS_XT, TRES, XRES, x, tt, c0, acc4);
    u16 packed[4];
#pragma unroll
    for (int j = 0; j < 4; ++j) packed[j] = f2bf(acc4[j]);
    *(short4v*)((char*)sA + p * 512 + ((c0 * 2) ^ ((p & 7) << 4))) = *(short4v*)packed;
  }
  __syncthreads();

  const u16* wfb = ws + WS_WF;
  layer_gemm<1>(sA, sB, wfb + WF1, b1, wave, lane);
  __syncthreads();
  layer_gemm<8>(sB, sA, wfb + WF2, b2, wave, lane);
  __syncthreads();
  layer_gemm<8>(sA, sB, wfb + WF3, b3, wave, lane);
  __syncthreads();

  // final layer: 256 -> 2, sigmoid. 8 threads per point, 32 k's each.
  {
    const int p = t >> 3, cg = t & 7;
    const int pg = pg0 + p;
    float a0 = 0.f, a1 = 0.f;
#pragma unroll
    for (int kk = 0; kk < 4; ++kk) {
      const int k0 = cg * 32 + kk * 8;
      short8 h = *(const short8*)((const char*)sB + p * 512 + ((k0 * 2) ^ ((p & 7) << 4)));
#pragma unroll
      for (int j = 0; j < 8; ++j) {
        const float hv = bf2f((u16)h[j]);
        a0 = fmaf(hv, w4[(k0 + j) * 2 + 0], a0);
        a1 = fmaf(hv, w4[(k0 + j) * 2 + 1], a1);
      }
    }
    a0 += __shfl_xor(a0, 1, 8); a0 += __shfl_xor(a0, 2, 8); a0 += __shfl_xor(a0, 4, 8);
    a1 += __shfl_xor(a1, 1, 8); a1 += __shfl_xor(a1, 2, 8); a1 += __shfl_xor(a1, 4, 8);
    if (cg == 0) {
      const float o0 = 1.f / (1.f + __expf(-(a0 + b4[0])));
      const float o1 = 1.f / (1.f + __expf(-(a1 + b4[1])));
      *(float2*)(out + pg * 2) = make_float2(o0, o1);
    }
  }
}

extern "C" void kernel_launch(void* const* d_in, const int* in_sizes, int n_in,
                              void* d_out, int out_size, void* d_ws, size_t ws_size,
                              hipStream_t stream) {
  (void)in_sizes; (void)n_in; (void)out_size;
  const float* coords = (const float*)d_in[0];
  const float* xy = (const float*)d_in[1];
  const float* yt = (const float*)d_in[2];
  const float* xt = (const float*)d_in[3];
  const float* w1 = (const float*)d_in[4];
  const float* b1 = (const float*)d_in[5];
  const float* w2 = (const float*)d_in[6];
  const float* b2 = (const float*)d_in[7];
  const float* w3 = (const float*)d_in[8];
  const float* b3 = (const float*)d_in[9];
  const float* w4 = (const float*)d_in[10];
  const float* b4 = (const float*)d_in[11];

  if (ws_size >= WS_NEEDED_BYTES && d_ws != nullptr) {
    u16* ws = (u16*)d_ws;
    prep_planes<<<1280, 256, 0, stream>>>(xy, yt, xt, ws);
    prep_weights<<<68, 256, 0, stream>>>(w1, w2, w3, ws + WS_WF);
    triplane_fused<<<32768, 256, 0, stream>>>(coords, ws, b1, b2, b3, w4, b4, (float*)d_out);
  } else {
    triplane_safe<<<4096, 256, 0, stream>>>(coords, xy, yt, xt, w1, b1, w2, b2, w3, b3, w4, b4,
                                            (float*)d_out);
  }
}

// Round 7
// 573.362 us; speedup vs baseline: 1.7732x; 1.1842x over previous
//
#include <hip/hip_runtime.h>

typedef unsigned short u16;
typedef unsigned int u32;
typedef float f32x4 __attribute__((ext_vector_type(4)));
typedef short short8 __attribute__((ext_vector_type(8)));
typedef short short4v __attribute__((ext_vector_type(4)));

#define XRES 512
#define TRES 64

// ws layout in u16 elements
#define WS_XY 0
#define WS_YT 8388608
#define WS_XT 9437184
#define WS_WF 10485760
#define WF1 0
#define WF2 8192
#define WF3 73728
#define WS_NEEDED_BYTES 21250048ull

__device__ __forceinline__ u16 f2bf(float f) {
  union { float f; unsigned u; } v; v.f = f;
  unsigned r = v.u + 0x7FFFu + ((v.u >> 16) & 1u);
  return (u16)(r >> 16);
}
__device__ __forceinline__ float bf2f(u16 u) {
  union { unsigned u; float f; } v; v.u = ((unsigned)u) << 16;
  return v.f;
}
// packed f32x2 -> bf16x2 (RNE) in one instruction (plain VALU op, fully interlocked)
__device__ __forceinline__ u32 cvtpk_bf16(float lo, float hi) {
  u32 d;
  asm("v_cvt_pk_bf16_f32 %0, %1, %2" : "=v"(d) : "v"(lo), "v"(hi));
  return d;
}

// MFMA via the compiler builtin: hazard recognizer inserts required wait-states,
// regalloc cannot overlap D with A/B (the r6 nondeterminism source).
__device__ __forceinline__ f32x4 mfma16x16x32_bf16(short8 a, short8 b, f32x4 c) {
  return __builtin_amdgcn_mfma_f32_16x16x32_bf16(a, b, c, 0, 0, 0);
}

// ======================= FALLBACK KERNEL (pure VALU, used only if ws too small) ===============
__device__ __forceinline__ void sample_direct(const float* __restrict__ pl, int H, int W,
                                              float gx, float gy, float* acc) {
  float ix = (gx + 1.0f) * 0.5f * (float)(W - 1);
  float iy = (gy + 1.0f) * 0.5f * (float)(H - 1);
  float x0f = floorf(ix), y0f = floorf(iy);
  float wx = ix - x0f, wy = iy - y0f;
  int x0 = (int)x0f, y0 = (int)y0f;
  x0 = max(0, min(x0, W - 1)); y0 = max(0, min(y0, H - 1));
  int x1 = min(x0 + 1, W - 1), y1 = min(y0 + 1, H - 1);
  float w00 = (1.0f - wx) * (1.0f - wy), w01 = wx * (1.0f - wy);
  float w10 = (1.0f - wx) * wy,          w11 = wx * wy;
  const int HW = H * W;
  const int i00 = y0 * W + x0, i01 = y0 * W + x1, i10 = y1 * W + x0, i11 = y1 * W + x1;
#pragma unroll
  for (int c = 0; c < 32; ++c) {
    const float* pc = pl + c * HW;
    acc[c] += w00 * pc[i00] + w01 * pc[i01] + w10 * pc[i10] + w11 * pc[i11];
  }
}

__device__ void layer_valu(const float* hin, float* hout, const float* __restrict__ w,
                           const float* __restrict__ b) {
  for (int pass = 0; pass < 8; ++pass) {
    float acc[32];
#pragma unroll
    for (int jx = 0; jx < 32; ++jx) acc[jx] = b[pass * 32 + jx];
    for (int k = 0; k < 256; ++k) {
      const float hk = hin[k];
      const float* wr = w + k * 256 + pass * 32;
#pragma unroll
      for (int jx = 0; jx < 32; ++jx) acc[jx] = fmaf(hk, wr[jx], acc[jx]);
    }
#pragma unroll
    for (int jx = 0; jx < 32; ++jx) {
      float v = acc[jx];
      hout[pass * 32 + jx] = v > 0.f ? v : 0.01f * v;
    }
  }
}

__global__ void triplane_safe(const float* __restrict__ coords,
                              const float* __restrict__ xy, const float* __restrict__ yt,
                              const float* __restrict__ xt,
                              const float* __restrict__ w1, const float* __restrict__ b1,
                              const float* __restrict__ w2, const float* __restrict__ b2,
                              const float* __restrict__ w3, const float* __restrict__ b3,
                              const float* __restrict__ w4, const float* __restrict__ b4,
                              float* __restrict__ out) {
  const int pg = blockIdx.x * 256 + threadIdx.x;
  const float x  = coords[pg * 3 + 0];
  const float y  = coords[pg * 3 + 1];
  const float tt = coords[pg * 3 + 2];
  float feats[32];
#pragma unroll
  for (int c = 0; c < 32; ++c) feats[c] = 0.f;
  sample_direct(xy, XRES, XRES, x, y,  feats);
  sample_direct(yt, TRES, XRES, y, tt, feats);
  sample_direct(xt, TRES, XRES, x, tt, feats);

  float hA[256], hB[256];
  for (int pass = 0; pass < 8; ++pass) {
    float acc[32];
#pragma unroll
    for (int jx = 0; jx < 32; ++jx) acc[jx] = b1[pass * 32 + jx];
#pragma unroll
    for (int k = 0; k < 32; ++k) {
      const float fk = feats[k];
      const float* wr = w1 + k * 256 + pass * 32;
#pragma unroll
      for (int jx = 0; jx < 32; ++jx) acc[jx] = fmaf(fk, wr[jx], acc[jx]);
    }
#pragma unroll
    for (int jx = 0; jx < 32; ++jx) {
      float v = acc[jx];
      hA[pass * 32 + jx] = v > 0.f ? v : 0.01f * v;
    }
  }
  layer_valu(hA, hB, w2, b2);
  layer_valu(hB, hA, w3, b3);
  float a0 = b4[0], a1 = b4[1];
  for (int k = 0; k < 256; ++k) {
    a0 = fmaf(hA[k], w4[k * 2 + 0], a0);
    a1 = fmaf(hA[k], w4[k * 2 + 1], a1);
  }
  out[pg * 2 + 0] = 1.f / (1.f + __expf(-a0));
  out[pg * 2 + 1] = 1.f / (1.f + __expf(-a1));
}

// ======================= FAST PATH =======================
__global__ void prep_planes(const float* __restrict__ xy, const float* __restrict__ yt,
                            const float* __restrict__ xt, u16* __restrict__ ws) {
  int i = blockIdx.x * 256 + threadIdx.x;  // 0..327679
  const float* src; u16* dst; int HW; int idx;
  if (i < 262144)      { src = xy; dst = ws + WS_XY; HW = 262144; idx = i; }
  else if (i < 294912) { src = yt; dst = ws + WS_YT; HW = 32768;  idx = i - 262144; }
  else                 { src = xt; dst = ws + WS_XT; HW = 32768;  idx = i - 294912; }
  u16 tmp[32];
#pragma unroll
  for (int c = 0; c < 32; ++c) tmp[c] = f2bf(src[c * HW + idx]);
  short8* o = (short8*)(dst + (long)idx * 32);
#pragma unroll
  for (int s = 0; s < 4; ++s) o[s] = *(short8*)(tmp + s * 8);
}

// weights [K,256] f32 -> B-fragment chunks: chunk L=(CT*KSTEPS+ks)*64+lane holds 8 bf16
// w[k][col], col=CT*16+(lane&15), k=ks*32+(lane>>4)*8+j  (same slot->k map as A side)
__global__ void prep_weights(const float* __restrict__ w1, const float* __restrict__ w2,
                             const float* __restrict__ w3, u16* __restrict__ wf) {
  int tid = blockIdx.x * 256 + threadIdx.x;  // 0..17407
  const float* src; int KS; int local; int dstbase;
  if (tid < 1024)      { src = w1; KS = 1; local = tid;        dstbase = WF1; }
  else if (tid < 9216) { src = w2; KS = 8; local = tid - 1024; dstbase = WF2; }
  else                 { src = w3; KS = 8; local = tid - 9216; dstbase = WF3; }
  int lane = local & 63, blk = local >> 6;
  int ks = blk % KS, CT = blk / KS;
  int col = CT * 16 + (lane & 15);
  int kb = ks * 32 + (lane >> 4) * 8;
  u16 tmp[8];
#pragma unroll
  for (int j = 0; j < 8; ++j) tmp[j] = f2bf(src[(kb + j) * 256 + col]);
  *(short8*)(wf + dstbase + local * 8) = *(short8*)tmp;
}

// 4-channel bilinear sample from [H,W,C=32] bf16 plane
__device__ __forceinline__ void sample_plane4(const u16* __restrict__ pl, int H, int W,
                                              float gx, float gy, int c0, float* acc) {
  float ix = (gx + 1.0f) * 0.5f * (float)(W - 1);
  float iy = (gy + 1.0f) * 0.5f * (float)(H - 1);
  float x0f = floorf(ix), y0f = floorf(iy);
  float wx = ix - x0f, wy = iy - y0f;
  int x0 = (int)x0f, y0 = (int)y0f;
  x0 = max(0, min(x0, W - 1)); y0 = max(0, min(y0, H - 1));
  int x1 = min(x0 + 1, W - 1);
  int y1 = min(y0 + 1, H - 1);
  short4v v00 = *(const short4v*)(pl + (y0 * W + x0) * 32 + c0);
  short4v v01 = *(const short4v*)(pl + (y0 * W + x1) * 32 + c0);
  short4v v10 = *(const short4v*)(pl + (y1 * W + x0) * 32 + c0);
  short4v v11 = *(const short4v*)(pl + (y1 * W + x1) * 32 + c0);
  float w00 = (1.0f - wx) * (1.0f - wy), w01 = wx * (1.0f - wy);
  float w10 = (1.0f - wx) * wy,          w11 = wx * wy;
#pragma unroll
  for (int j = 0; j < 4; ++j)
    acc[j] += w00 * bf2f((u16)v00[j]) + w01 * bf2f((u16)v01[j])
            + w10 * bf2f((u16)v10[j]) + w11 * bf2f((u16)v11[j]);
}

// [64 x 32*KSTEPS] @ [32*KSTEPS x 256], bias-in-acc, leaky, bf16 out to LDS.
// LDS act layout: [64][256] bf16 rows (512 B), byte ^= ((row&7)<<4) XOR swizzle (T2).
// Wave w owns rows 0..63 x cols w*32..w*32+31 (4 rt x 2 ct).
// A (LDS) and B (global/L2) fragments double-buffered one ks-step ahead (T14).
template <int KSTEPS>
__device__ __forceinline__ void layer_gemm(const u16* src, u16* dst,
                                           const u16* __restrict__ wf,
                                           const float* __restrict__ bias,
                                           int wave, int lane) {
  const int r16 = lane & 15, kq = lane >> 4;
  f32x4 acc[4][2];
#pragma unroll
  for (int ct = 0; ct < 2; ++ct) {
    const float bv = bias[wave * 32 + ct * 16 + r16];
#pragma unroll
    for (int rt = 0; rt < 4; ++rt) acc[rt][ct] = (f32x4){bv, bv, bv, bv};
  }

  short8 aA[4], aB[4], bA[2], bB[2];

#define LDA(ks, dst_)                                                                   \
  {                                                                                     \
    const int kbyte_ = (ks) * 64 + kq * 16;                                             \
    _Pragma("unroll") for (int rt = 0; rt < 4; ++rt) {                                  \
      const int row_ = rt * 16 + r16;                                                   \
      dst_[rt] = *(const short8*)((const char*)src + row_ * 512 +                       \
                                  (kbyte_ ^ ((row_ & 7) << 4)));                        \
    }                                                                                   \
  }
#define LDB(ks, dst_)                                                                   \
  {                                                                                     \
    _Pragma("unroll") for (int ct = 0; ct < 2; ++ct)                                    \
        dst_[ct] = *(const short8*)(wf + (((wave * 2 + ct) * KSTEPS + (ks)) * 64 +      \
                                          lane) * 8);                                   \
  }

  LDA(0, aA); LDB(0, bA);
#pragma unroll
  for (int ks = 0; ks < KSTEPS; ++ks) {
    const bool even = (ks & 1) == 0;
    short8* ac = even ? aA : aB;
    short8* bc = even ? bA : bB;
    short8* an = even ? aB : aA;
    short8* bn = even ? bB : bA;
    if (ks + 1 < KSTEPS) { LDA(ks + 1, an); LDB(ks + 1, bn); }
#pragma unroll
    for (int rt = 0; rt < 4; ++rt)
#pragma unroll
      for (int ct = 0; ct < 2; ++ct)
        acc[rt][ct] = mfma16x16x32_bf16(ac[rt], bc[ct], acc[rt][ct]);
  }
#undef LDA
#undef LDB

  // C/D layout: col = lane&15, row = (lane>>4)*4 + reg  [m89-verified]
#pragma unroll
  for (int ct = 0; ct < 2; ++ct) {
    const int col = wave * 32 + ct * 16 + r16;
#pragma unroll
    for (int rt = 0; rt < 4; ++rt) {
#pragma unroll
      for (int qp = 0; qp < 2; ++qp) {
        float v0 = acc[rt][ct][qp * 2 + 0];
        float v1 = acc[rt][ct][qp * 2 + 1];
        v0 = fmaxf(v0, 0.01f * v0);
        v1 = fmaxf(v1, 0.01f * v1);
        const u32 pk = cvtpk_bf16(v0, v1);
        const int row0 = rt * 16 + kq * 4 + qp * 2;
        const int row1 = row0 + 1;
        *(u16*)((char*)dst + row0 * 512 + ((col * 2) ^ ((row0 & 7) << 4))) = (u16)pk;
        *(u16*)((char*)dst + row1 * 512 + ((col * 2) ^ ((row1 & 7) << 4))) = (u16)(pk >> 16);
      }
    }
  }
}

// fused main kernel: 64 points / block, 512 threads (8 waves), 64 KiB LDS
__global__ __launch_bounds__(512, 4) void triplane_fused(
    const float* __restrict__ coords, const u16* __restrict__ ws,
    const float* __restrict__ b1, const float* __restrict__ b2,
    const float* __restrict__ b3, const float* __restrict__ w4,
    const float* __restrict__ b4, float* __restrict__ out) {
  __shared__ u16 sA[64 * 256];
  __shared__ u16 sB[64 * 256];
  const int t = threadIdx.x;
  const int lane = t & 63, wave = t >> 6;
  const int pg0 = blockIdx.x * 64;

  // sampling: all 512 threads — 8 channel-groups of 4 per point
  {
    const int p = t >> 3, cg = t & 7, c0 = cg * 4;
    const int pg = pg0 + p;
    const float x  = coords[pg * 3 + 0];
    const float y  = coords[pg * 3 + 1];
    const float tt = coords[pg * 3 + 2];
    float acc4[4] = {0.f, 0.f, 0.f, 0.f};
    sample_plane4(ws + WS_XY, XRES, XRES, x, y,  c0, acc4);
    sample_plane4(ws + WS_YT, TRES, XRES, y, tt, c0, acc4);
    sample_plane4(ws + WS_XT, TRES, XRES, x, tt, c0, acc4);
    u16 packed[4];
#pragma unroll
    for (int j = 0; j < 4; ++j) packed[j] = f2bf(acc4[j]);
    *(short4v*)((char*)sA + p * 512 + ((c0 * 2) ^ ((p & 7) << 4))) = *(short4v*)packed;
  }
  __syncthreads();

  const u16* wfb = ws + WS_WF;
  layer_gemm<1>(sA, sB, wfb + WF1, b1, wave, lane);
  __syncthreads();
  layer_gemm<8>(sB, sA, wfb + WF2, b2, wave, lane);
  __syncthreads();
  layer_gemm<8>(sA, sB, wfb + WF3, b3, wave, lane);
  __syncthreads();

  // final layer: 256 -> 2, sigmoid. 8 threads per point, 32 k's each.
  {
    const int p = t >> 3, cg = t & 7;
    const int pg = pg0 + p;
    float a0 = 0.f, a1 = 0.f;
#pragma unroll
    for (int kk = 0; kk < 4; ++kk) {
      const int k0 = cg * 32 + kk * 8;
      short8 h = *(const short8*)((const char*)sB + p * 512 + ((k0 * 2) ^ ((p & 7) << 4)));
#pragma unroll
      for (int j = 0; j < 8; ++j) {
        const float hv = bf2f((u16)h[j]);
        a0 = fmaf(hv, w4[(k0 + j) * 2 + 0], a0);
        a1 = fmaf(hv, w4[(k0 + j) * 2 + 1], a1);
      }
    }
    a0 += __shfl_xor(a0, 1, 8); a0 += __shfl_xor(a0, 2, 8); a0 += __shfl_xor(a0, 4, 8);
    a1 += __shfl_xor(a1, 1, 8); a1 += __shfl_xor(a1, 2, 8); a1 += __shfl_xor(a1, 4, 8);
    if (cg == 0) {
      const float o0 = 1.f / (1.f + __expf(-(a0 + b4[0])));
      const float o1 = 1.f / (1.f + __expf(-(a1 + b4[1])));
      *(float2*)(out + pg * 2) = make_float2(o0, o1);
    }
  }
}

extern "C" void kernel_launch(void* const* d_in, const int* in_sizes, int n_in,
                              void* d_out, int out_size, void* d_ws, size_t ws_size,
                              hipStream_t stream) {
  (void)in_sizes; (void)n_in; (void)out_size;
  const float* coords = (const float*)d_in[0];
  const float* xy = (const float*)d_in[1];
  const float* yt = (const float*)d_in[2];
  const float* xt = (const float*)d_in[3];
  const float* w1 = (const float*)d_in[4];
  const float* b1 = (const float*)d_in[5];
  const float* w2 = (const float*)d_in[6];
  const float* b2 = (const float*)d_in[7];
  const float* w3 = (const float*)d_in[8];
  const float* b3 = (const float*)d_in[9];
  const float* w4 = (const float*)d_in[10];
  const float* b4 = (const float*)d_in[11];

  if (ws_size >= WS_NEEDED_BYTES && d_ws != nullptr) {
    u16* ws = (u16*)d_ws;
    prep_planes<<<1280, 256, 0, stream>>>(xy, yt, xt, ws);
    prep_weights<<<68, 256, 0, stream>>>(w1, w2, w3, ws + WS_WF);
    triplane_fused<<<16384, 512, 0, stream>>>(coords, ws, b1, b2, b3, w4, b4, (float*)d_out);
  } else {
    triplane_safe<<<4096, 256, 0, stream>>>(coords, xy, yt, xt, w1, b1, w2, b2, w3, b3, w4, b4,
                                            (float*)d_out);
  }
}